// Round 5
// baseline (14.074 us; speedup 1.0000x reference)
//
#include <hip/hip_runtime.h>

// InverseLoss: fused strain->stress->equilibrium-residual->scalar loss.
// H=W=256; data is (257*257, 2) interleaved (ux, uy); output is 1 float.
//
// Single plain dispatch. Block = one image row (256 blocks x 256 threads).
// Thread c computes the 3 stress rows it needs at col c ONCE into LDS
// (3 evals vs 8 redundant in R3; ~14 VMEM/thread vs ~57), then forms
// fx/fy from the LDS 3x3 window. Per-block partials go to unique ws slots
// (plain overwrite, replay-safe, no init). Grid-wide completion uses a
// WRAPPING release-counter: the block whose fetch_add returns old&255==255
// is last (works from any poison value, exactly one winner per call) and
// gathers+finalizes. No cooperative launch (R2: +30us), no spin (R3).

#define HH 256
#define WW 256
#define DPITCH 257  // displacement field is 257x257
#define NBLK 256

__global__ __launch_bounds__(256) void inverse_loss_onepass(
        const float* __restrict__ E, const float* __restrict__ V,
        const float* __restrict__ data, float* __restrict__ ws,
        float* __restrict__ out) {
    const int r = blockIdx.x;        // row
    const int c = threadIdx.x;       // col
    const float2* d2 = (const float2*)data;

    __shared__ float sxx[3][WW], syy[3][WW], sxy[3][WW], ecol[WW];

    float sE = E[r * WW + c];        // for loss_e = |mean(E) - 0.25|
    float ax = 0.f, ay = 0.f;

    if (r < HH - 2) {
        // displacement window: rows r..r+3, cols c,c+1 (c+1 <= 256 valid)
        float2 P[4], Q[4];
        #pragma unroll
        for (int m = 0; m < 4; ++m) {
            P[m] = d2[(r + m) * DPITCH + c];
            Q[m] = d2[(r + m) * DPITCH + c + 1];
        }
        float ecs = 0.f;
        #pragma unroll
        for (int k = 0; k < 3; ++k) {
            const float2 p00 = P[k],     p01 = Q[k];
            const float2 p10 = P[k + 1], p11 = Q[k + 1];
            const float exx = 50.f * ((p10.x + p11.x) - (p00.x + p01.x));
            const float eyy = 50.f * ((p00.y - p01.y) + (p10.y - p11.y));
            const float rxy = 50.f * ((p00.x - p01.x) + (p10.x - p11.x))
                            + 50.f * ((p10.y + p11.y) - (p00.y + p01.y));
            const int idx = (r + k) * WW + c;
            const float Ev = (k == 0) ? sE : E[idx];
            const float vv = V[idx];
            const float frac = Ev / (1.f - vv * vv);
            sxx[k][c] = (exx + vv * eyy) * frac;
            syy[k][c] = (vv * exx + eyy) * frac;
            sxy[k][c] = rxy * (1.f - vv) * 0.5f * frac;
            ecs += Ev;
        }
        ecol[c] = ecs;               // column sum of E rows r..r+2
    }
    __syncthreads();

    if (r < HH - 2 && c < WW - 2) {
        const float ec = ecol[c] + ecol[c + 1] + ecol[c + 2];
        // fx = conv(sxx, [[-1,-1,-1],[0,0,0],[1,1,1]]) + conv(sxy, [[1,0,-1]x3])
        const float fx = (sxx[2][c] + sxx[2][c+1] + sxx[2][c+2])
                       - (sxx[0][c] + sxx[0][c+1] + sxx[0][c+2])
                       + (sxy[0][c] + sxy[1][c] + sxy[2][c])
                       - (sxy[0][c+2] + sxy[1][c+2] + sxy[2][c+2]);
        // fy = conv(syy, [[1,0,-1]x3]) + conv(sxy, [[-1,-1,-1],[0,0,0],[1,1,1]])
        const float fy = (syy[0][c] + syy[1][c] + syy[2][c])
                       - (syy[0][c+2] + syy[1][c+2] + syy[2][c+2])
                       + (sxy[2][c] + sxy[2][c+1] + sxy[2][c+2])
                       - (sxy[0][c] + sxy[0][c+1] + sxy[0][c+2]);
        ax = fabsf(fx / ec);
        ay = fabsf(fy / ec);
    }

    // ---- block reduction: wave64 shuffle, then cross-wave via LDS ----
    #pragma unroll
    for (int off = 32; off > 0; off >>= 1) {
        ax += __shfl_down(ax, off);
        ay += __shfl_down(ay, off);
        sE += __shfl_down(sE, off);
    }
    __shared__ float red[3][4];
    __shared__ int is_last;
    const int wave = threadIdx.x >> 6;
    const int lane = threadIdx.x & 63;
    if (lane == 0) { red[0][wave] = ax; red[1][wave] = ay; red[2][wave] = sE; }
    __syncthreads();

    if (threadIdx.x == 0) {
        const float p0 = red[0][0] + red[0][1] + red[0][2] + red[0][3];
        const float p1 = red[1][0] + red[1][1] + red[1][2] + red[1][3];
        const float p2 = red[2][0] + red[2][1] + red[2][2] + red[2][3];
        const int b = blockIdx.x;
        __hip_atomic_store(&ws[b],            p0, __ATOMIC_RELAXED, __HIP_MEMORY_SCOPE_AGENT);
        __hip_atomic_store(&ws[NBLK + b],     p1, __ATOMIC_RELAXED, __HIP_MEMORY_SCOPE_AGENT);
        __hip_atomic_store(&ws[2 * NBLK + b], p2, __ATOMIC_RELAXED, __HIP_MEMORY_SCOPE_AGENT);
        // wrapping completion counter: works from ANY initial value (poison-
        // safe), exactly one block per call sees old&255==255.
        const unsigned old = __hip_atomic_fetch_add(
            (unsigned*)&ws[3 * NBLK], 1u, __ATOMIC_ACQ_REL, __HIP_MEMORY_SCOPE_AGENT);
        is_last = ((old & (NBLK - 1)) == (NBLK - 1)) ? 1 : 0;
    }
    __syncthreads();

    if (is_last) {
        // all 256 threads of the last-arriving block gather the partials
        const int i = threadIdx.x;
        float v0 = __hip_atomic_load(&ws[i],            __ATOMIC_RELAXED, __HIP_MEMORY_SCOPE_AGENT);
        float v1 = __hip_atomic_load(&ws[NBLK + i],     __ATOMIC_RELAXED, __HIP_MEMORY_SCOPE_AGENT);
        float v2 = __hip_atomic_load(&ws[2 * NBLK + i], __ATOMIC_RELAXED, __HIP_MEMORY_SCOPE_AGENT);
        #pragma unroll
        for (int off = 32; off > 0; off >>= 1) {
            v0 += __shfl_down(v0, off);
            v1 += __shfl_down(v1, off);
            v2 += __shfl_down(v2, off);
        }
        __shared__ float red2[3][4];
        if (lane == 0) { red2[0][wave] = v0; red2[1][wave] = v1; red2[2][wave] = v2; }
        __syncthreads();
        if (threadIdx.x == 0) {
            const float gx = red2[0][0] + red2[0][1] + red2[0][2] + red2[0][3];
            const float gy = red2[1][0] + red2[1][1] + red2[1][2] + red2[1][3];
            const float gE = red2[2][0] + red2[2][1] + red2[2][2] + red2[2][3];
            const float npix = (float)((HH - 2) * (WW - 2));
            out[0] = gx / npix + gy / npix
                   + fabsf(gE * (1.f / (HH * WW)) - 0.25f) * 0.01f;
        }
    }
}

extern "C" void kernel_launch(void* const* d_in, const int* in_sizes, int n_in,
                              void* d_out, int out_size, void* d_ws, size_t ws_size,
                              hipStream_t stream) {
    const float* E    = (const float*)d_in[0];
    const float* V    = (const float*)d_in[1];
    const float* data = (const float*)d_in[2];
    float* out = (float*)d_out;
    float* ws  = (float*)d_ws;
    inverse_loss_onepass<<<dim3(NBLK), dim3(256), 0, stream>>>(E, V, data, ws, out);
}

// Round 6
// 10.935 us; speedup vs baseline: 1.2870x; 1.2870x over previous
//
#include <hip/hip_runtime.h>

// InverseLoss: fused strain->stress->equilibrium-residual->scalar loss.
// H=W=256; data is (257*257, 2) interleaved (ux, uy); output is 1 float.
//
// R3 structure (best so far: single plain dispatch, redundant per-thread
// recompute = max MLP, no intra-compute barriers, spin-tag finalize) with
// per-thread work cut: register 4x4 data window (33 VMEM vs ~57), and the
// two output divides folded into one ((|fx|+|fy|)/ec, valid since ec>0),
// reducing to 2 reduction chains. R4 lesson: LDS staging + barrier destroys
// latency hiding at 1 wave/SIMD; R2 lesson: cooperative launch +30us.

#define HH 256
#define WW 256
#define DPITCH 257  // displacement field is 257x257
#define NBLK 256
#define TAG_MAGIC 0x5BD1E995u

__global__ __launch_bounds__(256) void inverse_loss_onepass(
        const float* __restrict__ E, const float* __restrict__ V,
        const float* __restrict__ data, float* __restrict__ ws,
        float* __restrict__ out) {
    const int t = blockIdx.x * 256 + threadIdx.x;   // grid covers 256x256
    const int r = t >> 8;
    const int c = t & 255;
    const float2* d2 = (const float2*)data;

    float sE = E[t];            // for loss_e = |mean(E) - 0.25|
    float sxy_sum = 0.f;        // (|fx| + |fy|) / ec contribution

    if (r < HH - 2 && c < WW - 2) {
        // ---- one batch of independent loads (MLP): 16 + 9 + 8 VMEM ----
        float2 W[4][4];                     // displacement rows r..r+3, cols c..c+3
        #pragma unroll
        for (int m = 0; m < 4; ++m)
            #pragma unroll
            for (int n = 0; n < 4; ++n)
                W[m][n] = d2[(r + m) * DPITCH + c + n];
        float Ew[3][3], Vw[3][3];
        #pragma unroll
        for (int k = 0; k < 3; ++k)
            #pragma unroll
            for (int j = 0; j < 3; ++j) {
                const int idx = (r + k) * WW + (c + j);
                Ew[k][j] = (k == 0 && j == 0) ? sE : E[idx];
                if (!(k == 1 && j == 1)) Vw[k][j] = V[idx];  // center unused
            }

        // ---- stress at the 8 border pixels of the 3x3 window ----
        float sxx[3][3], syy[3][3], sxy[3][3];
        float ec = 0.f;
        #pragma unroll
        for (int k = 0; k < 3; ++k) {
            #pragma unroll
            for (int j = 0; j < 3; ++j) {
                ec += Ew[k][j];
                if (k == 1 && j == 1) continue;
                const float2 p00 = W[k][j],     p01 = W[k][j + 1];
                const float2 p10 = W[k + 1][j], p11 = W[k + 1][j + 1];
                const float exx = 50.f * ((p10.x + p11.x) - (p00.x + p01.x));
                const float eyy = 50.f * ((p00.y - p01.y) + (p10.y - p11.y));
                const float rxy = 50.f * ((p00.x - p01.x) + (p10.x - p11.x))
                                + 50.f * ((p10.y + p11.y) - (p00.y + p01.y));
                const float Ev = Ew[k][j];
                const float vv = Vw[k][j];
                const float frac = Ev / (1.f - vv * vv);
                sxx[k][j] = (exx + vv * eyy) * frac;
                syy[k][j] = (vv * exx + eyy) * frac;
                sxy[k][j] = rxy * (1.f - vv) * 0.5f * frac;
            }
        }
        const float fx = (sxx[2][0] + sxx[2][1] + sxx[2][2])
                       - (sxx[0][0] + sxx[0][1] + sxx[0][2])
                       + (sxy[0][0] + sxy[1][0] + sxy[2][0])
                       - (sxy[0][2] + sxy[1][2] + sxy[2][2]);
        const float fy = (syy[0][0] + syy[1][0] + syy[2][0])
                       - (syy[0][2] + syy[1][2] + syy[2][2])
                       + (sxy[2][0] + sxy[2][1] + sxy[2][2])
                       - (sxy[0][0] + sxy[0][1] + sxy[0][2]);
        // ec > 0 (E in [0.05,0.5]) -> |fx/ec|+|fy/ec| == (|fx|+|fy|)/ec
        sxy_sum = (fabsf(fx) + fabsf(fy)) / ec;
    }

    // ---- block reduction: wave64 shuffle, then cross-wave via LDS ----
    #pragma unroll
    for (int off = 32; off > 0; off >>= 1) {
        sxy_sum += __shfl_down(sxy_sum, off);
        sE      += __shfl_down(sE, off);
    }
    __shared__ float red[2][4];
    const int wave = threadIdx.x >> 6;
    const int lane = threadIdx.x & 63;
    if (lane == 0) { red[0][wave] = sxy_sum; red[1][wave] = sE; }
    __syncthreads();

    if (threadIdx.x == 0) {
        const float p0 = red[0][0] + red[0][1] + red[0][2] + red[0][3];
        const float p1 = red[1][0] + red[1][1] + red[1][2] + red[1][3];
        const int b = blockIdx.x;
        __hip_atomic_store(&ws[b],        p0, __ATOMIC_RELAXED, __HIP_MEMORY_SCOPE_AGENT);
        __hip_atomic_store(&ws[NBLK + b], p1, __ATOMIC_RELAXED, __HIP_MEMORY_SCOPE_AGENT);
        const unsigned tag = __float_as_uint(p0) ^ __float_as_uint(p1) ^ TAG_MAGIC;
        __hip_atomic_store((unsigned*)&ws[2 * NBLK + b], tag,
                           __ATOMIC_RELEASE, __HIP_MEMORY_SCOPE_AGENT);
    }

    if (blockIdx.x == 0) {
        // thread i owns block i's partials: spin until tag validates values.
        const int i = threadIdx.x;
        float v0, v1;
        unsigned tag;
        do {
            tag = __hip_atomic_load((const unsigned*)&ws[2 * NBLK + i],
                                    __ATOMIC_ACQUIRE, __HIP_MEMORY_SCOPE_AGENT);
            v0 = __hip_atomic_load(&ws[i],        __ATOMIC_RELAXED, __HIP_MEMORY_SCOPE_AGENT);
            v1 = __hip_atomic_load(&ws[NBLK + i], __ATOMIC_RELAXED, __HIP_MEMORY_SCOPE_AGENT);
        } while (tag != (__float_as_uint(v0) ^ __float_as_uint(v1) ^ TAG_MAGIC));

        #pragma unroll
        for (int off = 32; off > 0; off >>= 1) {
            v0 += __shfl_down(v0, off);
            v1 += __shfl_down(v1, off);
        }
        __shared__ float red2[2][4];
        if (lane == 0) { red2[0][wave] = v0; red2[1][wave] = v1; }
        __syncthreads();
        if (threadIdx.x == 0) {
            const float gs = red2[0][0] + red2[0][1] + red2[0][2] + red2[0][3];
            const float gE = red2[1][0] + red2[1][1] + red2[1][2] + red2[1][3];
            const float npix = (float)((HH - 2) * (WW - 2));
            out[0] = gs / npix
                   + fabsf(gE * (1.f / (HH * WW)) - 0.25f) * 0.01f;
        }
    }
}

extern "C" void kernel_launch(void* const* d_in, const int* in_sizes, int n_in,
                              void* d_out, int out_size, void* d_ws, size_t ws_size,
                              hipStream_t stream) {
    const float* E    = (const float*)d_in[0];
    const float* V    = (const float*)d_in[1];
    const float* data = (const float*)d_in[2];
    float* out = (float*)d_out;
    float* ws  = (float*)d_ws;
    inverse_loss_onepass<<<dim3(NBLK), dim3(256), 0, stream>>>(E, V, data, ws, out);
}